// Round 13
// baseline (281.806 us; speedup 1.0000x reference)
//
#include <hip/hip_runtime.h>
#include <math.h>

#define NTOK   262144
#define DIM    64
#define NCODE  1024
#define LOSSOFF (NTOK*DIM)          // 16777216
#define IDXOFF  (NTOK*DIM + 1)

#define MARGIN 1e-4f
#define RCAP   65536

// ws float-offsets
#define OFF_BC     0               // 1024 f
#define OFF_CBHI   1024            // ushort[65536] = 32768 f
#define OFF_CBMID  33792           // 32768 f
#define OFF_RCNT   66560           // 1 int
#define OFF_CORR   66561           // 1 float
#define OFF_RLIST  66562           // 65536 int
#define OFF_BLK    132098          // 1024 f
#define WS_FLOATS  133122

typedef __attribute__((ext_vector_type(8))) short short8;
typedef __attribute__((ext_vector_type(4))) float f32x4;

__device__ __forceinline__ ushort bf16rn(float f) {
    unsigned u = __float_as_uint(f);
    return (ushort)((u + 0x7fffu + ((u >> 16) & 1u)) >> 16);
}
__device__ __forceinline__ float bf16tof(ushort h) {
    return __uint_as_float(((unsigned)h) << 16);
}

__global__ __launch_bounds__(256) void vq_prep_cb(const float* __restrict__ cb,
                                                  float* __restrict__ ws) {
    int c = blockIdx.x * 256 + threadIdx.x;
    if (c == 0) { ((int*)ws)[OFF_RCNT] = 0; ws[OFF_CORR] = 0.f; }
    if (c >= NCODE) return;
    ushort* cbh = (ushort*)(ws + OFF_CBHI);
    ushort* cbm = (ushort*)(ws + OFF_CBMID);
    const float4* p = (const float4*)(cb + (size_t)c * DIM);
    float a0 = 0.f, a1 = 0.f, a2 = 0.f, a3 = 0.f;
#pragma unroll
    for (int i = 0; i < 16; i++) {
        float4 v = p[i];
        a0 = fmaf(v.x, v.x, a0); a1 = fmaf(v.y, v.y, a1);
        a2 = fmaf(v.z, v.z, a2); a3 = fmaf(v.w, v.w, a3);
        ushort4 h, m;
        h.x = bf16rn(v.x); m.x = bf16rn(v.x - bf16tof(h.x));
        h.y = bf16rn(v.y); m.y = bf16rn(v.y - bf16tof(h.y));
        h.z = bf16rn(v.z); m.z = bf16rn(v.z - bf16tof(h.z));
        h.w = bf16rn(v.w); m.w = bf16rn(v.w - bf16tof(h.w));
        ((ushort4*)(cbh + (size_t)c * 64))[i] = h;
        ((ushort4*)(cbm + (size_t)c * 64))[i] = m;
    }
    ws[OFF_BC + c] = (a0 + a1) + (a2 + a3);   // exact R2 prep chain
}

// Barrier-free MFMA distance pass: A-fragments gathered directly from the
// L2-resident split codebook (no LDS staging, no __syncthreads in the scan),
// one-tile-ahead register pipeline, 64 tokens per wave (4 token-tiles).
// Distance values bit-identical to the R12-verified kernel.
__global__ __launch_bounds__(256) void vq_mfma(const float* __restrict__ x,
                                               const float* __restrict__ cbf,
                                               float* __restrict__ out,
                                               float* __restrict__ ws) {
    __shared__ int idxs[256];
    __shared__ float red[4];
    const float* Bc = ws + OFF_BC;
    const ushort* cbh = (const ushort*)(ws + OFF_CBHI);
    const ushort* cbm = (const ushort*)(ws + OFF_CBMID);

    int tid = threadIdx.x, lane = tid & 63, wv = tid >> 6;
    int col = lane & 15, q = lane >> 4, q4 = q * 4;
    int tokb = blockIdx.x * 256 + wv * 64;

    // X fragments for 4 token-tiles (all indices compile-time -> registers)
    short8 Xhi[4][2], Xmid[4][2];
#pragma unroll
    for (int tt = 0; tt < 4; ++tt) {
        int token = tokb + tt * 16 + col;
        const float* xr = x + (size_t)token * 64;
#pragma unroll
        for (int s = 0; s < 2; ++s) {
            float4 v0 = *(const float4*)(xr + s * 32 + q * 8);
            float4 v1 = *(const float4*)(xr + s * 32 + q * 8 + 4);
            float vv[8] = {v0.x, v0.y, v0.z, v0.w, v1.x, v1.y, v1.z, v1.w};
            short8 hv, mv;
#pragma unroll
            for (int j = 0; j < 8; ++j) {
                ushort h = bf16rn(vv[j]);
                float r = vv[j] - bf16tof(h);   // exact (Sterbenz)
                hv[j] = (short)h; mv[j] = (short)bf16rn(r);
            }
            Xhi[tt][s] = hv; Xmid[tt][s] = mv;
        }
    }

    float best[4][4], sec[4][4];
    int bbase[4][4];
#pragma unroll
    for (int tt = 0; tt < 4; ++tt)
#pragma unroll
        for (int rr = 0; rr < 4; ++rr) {
            best[tt][rr] = 3.4e38f; sec[tt][rr] = 3.4e38f; bbase[tt][rr] = 0;
        }

    // per-lane gather base: row col, elements q*8.. (hi) / +32 (second K-half)
    const ushort* ph = cbh + col * 64 + q * 8;
    const ushort* pm = cbm + col * 64 + q * 8;

    // one-tile-ahead register pipeline (tile stride = 1024 ushorts)
    uint4 gh0 = *(const uint4*)(ph);
    uint4 gh1 = *(const uint4*)(ph + 32);
    uint4 gm0 = *(const uint4*)(pm);
    uint4 gm1 = *(const uint4*)(pm + 32);
    float4 gbq = *(const float4*)(Bc + q4);

    for (int t = 0; t < 64; ++t) {
        short8 Ah0 = __builtin_bit_cast(short8, gh0);
        short8 Ah1 = __builtin_bit_cast(short8, gh1);
        short8 Am0 = __builtin_bit_cast(short8, gm0);
        short8 Am1 = __builtin_bit_cast(short8, gm1);
        float4 bq = gbq;
        if (t < 63) {   // prefetch next tile; one full tile of compute as slack
            const ushort* phn = ph + (t + 1) * 1024;
            const ushort* pmn = pm + (t + 1) * 1024;
            gh0 = *(const uint4*)(phn);
            gh1 = *(const uint4*)(phn + 32);
            gm0 = *(const uint4*)(pmn);
            gm1 = *(const uint4*)(pmn + 32);
            gbq = *(const float4*)(Bc + (t + 1) * 16 + q4);
        }
        int bv = t * 16 + q4;
        float bqv[4] = {bq.x, bq.y, bq.z, bq.w};
#pragma unroll
        for (int tt = 0; tt < 4; ++tt) {
            f32x4 acc = {0.f, 0.f, 0.f, 0.f};
            acc = __builtin_amdgcn_mfma_f32_16x16x32_bf16(Ah0, Xhi[tt][0], acc, 0, 0, 0);
            acc = __builtin_amdgcn_mfma_f32_16x16x32_bf16(Ah1, Xhi[tt][1], acc, 0, 0, 0);
            acc = __builtin_amdgcn_mfma_f32_16x16x32_bf16(Ah0, Xmid[tt][0], acc, 0, 0, 0);
            acc = __builtin_amdgcn_mfma_f32_16x16x32_bf16(Ah1, Xmid[tt][1], acc, 0, 0, 0);
            acc = __builtin_amdgcn_mfma_f32_16x16x32_bf16(Am0, Xhi[tt][0], acc, 0, 0, 0);
            acc = __builtin_amdgcn_mfma_f32_16x16x32_bf16(Am1, Xhi[tt][1], acc, 0, 0, 0);
#pragma unroll
            for (int rr = 0; rr < 4; ++rr) {
                float d = fmaf(-2.f, acc[rr], bqv[rr]);
                bool lt = d < best[tt][rr];
                sec[tt][rr] = __builtin_amdgcn_fmed3f(d, best[tt][rr], sec[tt][rr]);
                best[tt][rr] = fminf(best[tt][rr], d);
                bbase[tt][rr] = lt ? bv : bbase[tt][rr];
            }
        }
    }

#pragma unroll
    for (int tt = 0; tt < 4; ++tt) {
        float b = best[tt][0], s2 = sec[tt][0];
        int bi = bbase[tt][0];
#pragma unroll
        for (int rr = 1; rr < 4; ++rr) {
            float ob = best[tt][rr];
            int oi = bbase[tt][rr] + rr;
            s2 = fminf(fminf(s2, sec[tt][rr]), fmaxf(b, ob));
            bool lt2 = (ob < b) || (ob == b && oi < bi);
            b = lt2 ? ob : b; bi = lt2 ? oi : bi;
        }
#pragma unroll
        for (int off = 16; off <= 32; off <<= 1) {
            float ob = __shfl_xor(b, off, 64);
            float os = __shfl_xor(s2, off, 64);
            int   oi = __shfl_xor(bi, off, 64);
            s2 = fminf(fminf(s2, os), fmaxf(b, ob));
            bool lt = (ob < b) || (ob == b && oi < bi);
            b = lt ? ob : b; bi = lt ? oi : bi;
        }
        if (lane < 16) {
            int token = tokb + tt * 16 + lane;
            out[IDXOFF + token] = (float)bi;
            idxs[wv * 64 + tt * 16 + lane] = bi;
            if (s2 - b < MARGIN) {
                int pos = atomicAdd((int*)ws + OFF_RCNT, 1);
                if (pos < RCAP) ((int*)ws)[OFF_RLIST + pos] = token;
            }
        }
    }
    __syncthreads();   // the only block-wide barrier

    // fused quantized + loss epilogue (refine corrects flagged rows later)
    float se = 0.f;
    int tokb0 = blockIdx.x * 256;
#pragma unroll
    for (int i = 0; i < 16; ++i) {
        int gi = i * 256 + tid;
        int tok = gi >> 4, qd = gi & 15;
        int ci = idxs[tok];
        float4 xvv = *(const float4*)(x + (size_t)(tokb0 + tok) * 64 + qd * 4);
        float4 qv = *(const float4*)(cbf + (size_t)ci * 64 + qd * 4);
        float d0 = qv.x - xvv.x, d1 = qv.y - xvv.y;
        float d2 = qv.z - xvv.z, d3 = qv.w - xvv.w;
        float4 o;
        o.x = xvv.x + d0; o.y = xvv.y + d1; o.z = xvv.z + d2; o.w = xvv.w + d3;
        *(float4*)(out + (size_t)(tokb0 + tok) * 64 + qd * 4) = o;
        se += d0 * d0 + d1 * d1 + d2 * d2 + d3 * d3;
    }
    for (int off = 32; off; off >>= 1) se += __shfl_down(se, off, 64);
    if (lane == 0) red[wv] = se;
    __syncthreads();
    if (tid == 0) ws[OFF_BLK + blockIdx.x] = (red[0] + red[1]) + (red[2] + red[3]);
}

// exact fp32 re-scan for flagged tokens; fixes quantized rows + loss delta.
__global__ __launch_bounds__(256) void vq_refine(const float* __restrict__ x,
                                                 const float* __restrict__ cb,
                                                 float* __restrict__ out,
                                                 float* __restrict__ ws) {
    __shared__ float ctile[128][64];               // 32KB
    __shared__ float xs[8][64];
    __shared__ float As[8];
    __shared__ int   tokid[8], oidx[8], nidx[8];
    __shared__ unsigned long long rkeys[8][128];   // 8KB
    __shared__ float dred[4];

    int cnt = min(((int*)ws)[OFF_RCNT], RCAP);
    if (cnt <= 0) return;
    int ngroups = (cnt + 7) >> 3;
    int tid = threadIdx.x;
    int code = tid & 127, th = tid >> 7;

    for (int grp = blockIdx.x; grp < ngroups; grp += gridDim.x) {
        if (tid < 8) {
            int i = grp * 8 + tid;
            int t = ((int*)ws)[OFF_RLIST + min(i, cnt - 1)];
            tokid[tid] = t;
            oidx[tid] = (int)out[IDXOFF + t];
        }
        __syncthreads();
#pragma unroll
        for (int it = 0; it < 2; ++it) {
            int idx = it * 256 + tid;
            xs[idx >> 6][idx & 63] = x[(size_t)tokid[idx >> 6] * 64 + (idx & 63)];
        }
        __syncthreads();
        if (tid < 8) {   // exact R2 A-chain
            float a0 = 0.f, a1 = 0.f, a2 = 0.f, a3 = 0.f;
#pragma unroll
            for (int kc = 0; kc < 16; ++kc) {
                float4 xk = *(const float4*)(xs[tid] + kc * 4);
                a0 = fmaf(xk.x, xk.x, a0); a1 = fmaf(xk.y, xk.y, a1);
                a2 = fmaf(xk.z, xk.z, a2); a3 = fmaf(xk.w, xk.w, a3);
            }
            As[tid] = (a0 + a1) + (a2 + a3);
        }

        unsigned long long bk[4] = {~0ull, ~0ull, ~0ull, ~0ull};
        int tb = th * 4;

        for (int pass = 0; pass < 8; ++pass) {
            int cbase = pass * 128;
            __syncthreads();
#pragma unroll
            for (int it = 0; it < 8; ++it) {
                int gi = it * 256 + tid;
                int cc = gi >> 4, qq = gi & 15;
                float4 v = *(const float4*)(cb + (size_t)(cbase + cc) * 64 + qq * 4);
                *(float4*)&ctile[cc][(qq ^ (cc & 15)) * 4] = v;
            }
            __syncthreads();

            float p0 = 0.f, p1 = 0.f, p2 = 0.f, p3 = 0.f;
#pragma unroll
            for (int qq = 0; qq < 16; ++qq) {
                float4 cv = *(const float4*)&ctile[code][(qq ^ (code & 15)) * 4];
                float4 x0 = *(const float4*)(xs[tb + 0] + qq * 4);
                float4 x1 = *(const float4*)(xs[tb + 1] + qq * 4);
                float4 x2 = *(const float4*)(xs[tb + 2] + qq * 4);
                float4 x3 = *(const float4*)(xs[tb + 3] + qq * 4);
                p0 = fmaf(x0.x, cv.x, p0); p0 = fmaf(x0.y, cv.y, p0);
                p0 = fmaf(x0.z, cv.z, p0); p0 = fmaf(x0.w, cv.w, p0);
                p1 = fmaf(x1.x, cv.x, p1); p1 = fmaf(x1.y, cv.y, p1);
                p1 = fmaf(x1.z, cv.z, p1); p1 = fmaf(x1.w, cv.w, p1);
                p2 = fmaf(x2.x, cv.x, p2); p2 = fmaf(x2.y, cv.y, p2);
                p2 = fmaf(x2.z, cv.z, p2); p2 = fmaf(x2.w, cv.w, p2);
                p3 = fmaf(x3.x, cv.x, p3); p3 = fmaf(x3.y, cv.y, p3);
                p3 = fmaf(x3.z, cv.z, p3); p3 = fmaf(x3.w, cv.w, p3);
            }
            float bn = ws[OFF_BC + cbase + code];
            int gcode = cbase + code;
            float pv[4] = {p0, p1, p2, p3};
#pragma unroll
            for (int j = 0; j < 4; ++j) {
                float s = As[tb + j] + bn;
                float d = fmaf(-2.0f, pv[j], s);   // == fl(s - 2p)
                unsigned long long key =
                    (((unsigned long long)__float_as_uint(d)) << 32) | (unsigned)gcode;
                bk[j] = min(bk[j], key);
            }
        }
        __syncthreads();
#pragma unroll
        for (int j = 0; j < 4; ++j) rkeys[tb + j][code] = bk[j];
        __syncthreads();

        int wv2 = tid >> 6, lane = tid & 63;
#pragma unroll
        for (int u = 0; u < 2; ++u) {
            int tt = wv2 * 2 + u;
            unsigned long long k = min(rkeys[tt][lane], rkeys[tt][lane + 64]);
#pragma unroll
            for (int off = 32; off; off >>= 1)
                k = min(k, (unsigned long long)__shfl_xor((long long)k, off, 64));
            if (lane == 0) {
                int ni = (int)(unsigned)(k & 0xffffffffull);
                nidx[tt] = ni;
                if (grp * 8 + tt < cnt) out[IDXOFF + tokid[tt]] = (float)ni;
            }
        }
        __syncthreads();

        float delta = 0.f;
        {
            int tok = tid >> 5, e2 = (tid & 31) * 2;
            if (grp * 8 + tok < cnt) {
                int nw = nidx[tok], od = oidx[tok];
                if (nw != od) {
                    float x0 = xs[tok][e2], x1 = xs[tok][e2 + 1];
                    float qn0 = cb[(size_t)nw * 64 + e2], qn1 = cb[(size_t)nw * 64 + e2 + 1];
                    float qo0 = cb[(size_t)od * 64 + e2], qo1 = cb[(size_t)od * 64 + e2 + 1];
                    float dn0 = qn0 - x0, dn1 = qn1 - x1;
                    float do0 = qo0 - x0, do1 = qo1 - x1;
                    out[(size_t)tokid[tok] * 64 + e2]     = x0 + dn0;
                    out[(size_t)tokid[tok] * 64 + e2 + 1] = x1 + dn1;
                    delta = (dn0 * dn0 + dn1 * dn1) - (do0 * do0 + do1 * do1);
                }
            }
        }
        for (int off = 32; off; off >>= 1) delta += __shfl_down(delta, off, 64);
        if ((tid & 63) == 0) dred[tid >> 6] = delta;
        __syncthreads();
        if (tid == 0) {
            float dsum = (dred[0] + dred[1]) + (dred[2] + dred[3]);
            if (dsum != 0.f) atomicAdd(ws + OFF_CORR, dsum);
        }
        __syncthreads();
    }
}

__global__ __launch_bounds__(256) void vq_loss2(float* __restrict__ out,
                                                const float* __restrict__ ws) {
    const float* blk = ws + OFF_BLK;
    __shared__ double sd[256];
    double s = 0.0;
    for (int i = threadIdx.x; i < 1024; i += 256) s += (double)blk[i];
    sd[threadIdx.x] = s;
    __syncthreads();
    for (int off = 128; off; off >>= 1) {
        if (threadIdx.x < off) sd[threadIdx.x] += sd[threadIdx.x + off];
        __syncthreads();
    }
    if (threadIdx.x == 0) {
        double tot = sd[0] + (double)ws[OFF_CORR];
        out[LOSSOFF] = (float)(1.25 * tot / ((double)NTOK * (double)DIM));
    }
}

extern "C" void kernel_launch(void* const* d_in, const int* in_sizes, int n_in,
                              void* d_out, int out_size, void* d_ws, size_t ws_size,
                              hipStream_t stream) {
    (void)in_sizes; (void)n_in; (void)out_size; (void)ws_size;
    const float* x = (const float*)d_in[0];
    const float* cb = (const float*)d_in[1];
    float* out = (float*)d_out;
    float* ws = (float*)d_ws;

    hipLaunchKernelGGL(vq_prep_cb, dim3(4), dim3(256), 0, stream, cb, ws);
    hipLaunchKernelGGL(vq_mfma, dim3(1024), dim3(256), 0, stream, x, cb, out, ws);
    hipLaunchKernelGGL(vq_refine, dim3(1024), dim3(256), 0, stream, x, cb, out, ws);
    hipLaunchKernelGGL(vq_loss2, dim3(1), dim3(256), 0, stream, out, ws);
}

// Round 14
// 252.443 us; speedup vs baseline: 1.1163x; 1.1163x over previous
//
#include <hip/hip_runtime.h>
#include <math.h>

#define NTOK   262144
#define DIM    64
#define NCODE  1024
#define LOSSOFF (NTOK*DIM)          // 16777216
#define IDXOFF  (NTOK*DIM + 1)

#define MARGIN 1e-4f
#define RCAP   65536

// ws float-offsets
#define OFF_BC     0               // 1024 f
#define OFF_CBHI   1024            // ushort[65536] = 32768 f
#define OFF_CBMID  33792           // 32768 f
#define OFF_RCNT   66560           // 1 int
#define OFF_CORR   66561           // 1 float
#define OFF_RLIST  66562           // 65536 int
#define OFF_BLK    132098          // 1024 f
#define WS_FLOATS  133122

typedef __attribute__((ext_vector_type(8))) short short8;
typedef __attribute__((ext_vector_type(4))) float f32x4;

__device__ __forceinline__ ushort bf16rn(float f) {
    unsigned u = __float_as_uint(f);
    return (ushort)((u + 0x7fffu + ((u >> 16) & 1u)) >> 16);
}
__device__ __forceinline__ float bf16tof(ushort h) {
    return __uint_as_float(((unsigned)h) << 16);
}

__global__ __launch_bounds__(256) void vq_prep_cb(const float* __restrict__ cb,
                                                  float* __restrict__ ws) {
    int c = blockIdx.x * 256 + threadIdx.x;
    if (c == 0) { ((int*)ws)[OFF_RCNT] = 0; ws[OFF_CORR] = 0.f; }
    if (c >= NCODE) return;
    ushort* cbh = (ushort*)(ws + OFF_CBHI);
    ushort* cbm = (ushort*)(ws + OFF_CBMID);
    const float4* p = (const float4*)(cb + (size_t)c * DIM);
    float a0 = 0.f, a1 = 0.f, a2 = 0.f, a3 = 0.f;
#pragma unroll
    for (int i = 0; i < 16; i++) {
        float4 v = p[i];
        a0 = fmaf(v.x, v.x, a0); a1 = fmaf(v.y, v.y, a1);
        a2 = fmaf(v.z, v.z, a2); a3 = fmaf(v.w, v.w, a3);
        ushort4 h, m;
        h.x = bf16rn(v.x); m.x = bf16rn(v.x - bf16tof(h.x));
        h.y = bf16rn(v.y); m.y = bf16rn(v.y - bf16tof(h.y));
        h.z = bf16rn(v.z); m.z = bf16rn(v.z - bf16tof(h.z));
        h.w = bf16rn(v.w); m.w = bf16rn(v.w - bf16tof(h.w));
        ((ushort4*)(cbh + (size_t)c * 64))[i] = h;
        ((ushort4*)(cbm + (size_t)c * 64))[i] = m;
    }
    ws[OFF_BC + c] = (a0 + a1) + (a2 + a3);   // exact R2 prep chain
}

// MFMA distance pass: R12-proven LDS staging (4-tile-deep), but 64 tokens
// per wave (4 token-tiles) -> 24 MFMAs per 4 ds_read_b128 (was 12): the LDS
// pipe drops below the MFMA pipe. Distances bit-identical to R12.
__global__ __launch_bounds__(256) void vq_mfma(const float* __restrict__ x,
                                               const float* __restrict__ cbf,
                                               float* __restrict__ out,
                                               float* __restrict__ ws) {
    __shared__ uint4 smem[4][256];   // 16KB: [tilebuf][chunk(2)][code(16)][granule(8)]
    __shared__ int idxs[256];
    __shared__ float red[4];
    const float* Bc = ws + OFF_BC;
    const ushort* cbh = (const ushort*)(ws + OFF_CBHI);
    const ushort* cbm = (const ushort*)(ws + OFF_CBMID);

    int tid = threadIdx.x, lane = tid & 63, wv = tid >> 6;
    int col = lane & 15, q = lane >> 4, q4 = q * 4;
    int tokb = blockIdx.x * 256 + wv * 64;

    short8 Xhi[4][2], Xmid[4][2];
#pragma unroll
    for (int tt = 0; tt < 4; ++tt) {
        int token = tokb + tt * 16 + col;
        const float* xr = x + (size_t)token * 64;
#pragma unroll
        for (int s = 0; s < 2; ++s) {
            float4 v0 = *(const float4*)(xr + s * 32 + q * 8);
            float4 v1 = *(const float4*)(xr + s * 32 + q * 8 + 4);
            float vv[8] = {v0.x, v0.y, v0.z, v0.w, v1.x, v1.y, v1.z, v1.w};
            short8 hv, mv;
#pragma unroll
            for (int j = 0; j < 8; ++j) {
                ushort h = bf16rn(vv[j]);
                float r = vv[j] - bf16tof(h);   // exact (Sterbenz)
                hv[j] = (short)h; mv[j] = (short)bf16rn(r);
            }
            Xhi[tt][s] = hv; Xmid[tt][s] = mv;
        }
    }

    float best[4][4], sec[4][4];
    int bbase[4][4];
#pragma unroll
    for (int tt = 0; tt < 4; ++tt)
#pragma unroll
        for (int rr = 0; rr < 4; ++rr) {
            best[tt][rr] = 3.4e38f; sec[tt][rr] = 3.4e38f; bbase[tt][rr] = 0;
        }

    int chunk = tid >> 7, e = tid & 127, scode = e >> 3, g = e & 7;
    const ushort* sb0 = (chunk ? cbm : cbh) + (size_t)scode * 64 + g * 8;
    int woff = chunk * 128 + scode * 8 + (g ^ (scode & 7));
    int ro_h0 = col * 8 + ((0 + q) ^ (col & 7));
    int ro_h1 = col * 8 + ((4 + q) ^ (col & 7));
    int ro_m0 = 128 + col * 8 + ((0 + q) ^ (col & 7));
    int ro_m1 = 128 + col * 8 + ((4 + q) ^ (col & 7));

    uint4 r0 = *(const uint4*)(sb0);
    uint4 r1 = *(const uint4*)(sb0 + 1024);
    uint4 r2 = *(const uint4*)(sb0 + 2048);
    uint4 r3 = *(const uint4*)(sb0 + 3072);
    smem[0][woff] = r0; smem[1][woff] = r1;
    smem[2][woff] = r2; smem[3][woff] = r3;
    __syncthreads();

    for (int t = 0; t < 64; t += 4) {
        if (t + 4 < 64) {   // prefetch next round; full-round slack
            r0 = *(const uint4*)(sb0 + (size_t)(t + 4) * 1024);
            r1 = *(const uint4*)(sb0 + (size_t)(t + 5) * 1024);
            r2 = *(const uint4*)(sb0 + (size_t)(t + 6) * 1024);
            r3 = *(const uint4*)(sb0 + (size_t)(t + 7) * 1024);
        }
#pragma unroll
        for (int sub = 0; sub < 4; ++sub) {
            int c0 = (t + sub) * 16;
            float4 bq = *(const float4*)(Bc + c0 + q4);
            short8 Ah0 = *(const short8*)&smem[sub][ro_h0];
            short8 Ah1 = *(const short8*)&smem[sub][ro_h1];
            short8 Am0 = *(const short8*)&smem[sub][ro_m0];
            short8 Am1 = *(const short8*)&smem[sub][ro_m1];
            int bv = c0 + q4;
            float bqv[4] = {bq.x, bq.y, bq.z, bq.w};
#pragma unroll
            for (int tt = 0; tt < 4; ++tt) {
                f32x4 acc = {0.f, 0.f, 0.f, 0.f};
                acc = __builtin_amdgcn_mfma_f32_16x16x32_bf16(Ah0, Xhi[tt][0], acc, 0, 0, 0);
                acc = __builtin_amdgcn_mfma_f32_16x16x32_bf16(Ah1, Xhi[tt][1], acc, 0, 0, 0);
                acc = __builtin_amdgcn_mfma_f32_16x16x32_bf16(Ah0, Xmid[tt][0], acc, 0, 0, 0);
                acc = __builtin_amdgcn_mfma_f32_16x16x32_bf16(Ah1, Xmid[tt][1], acc, 0, 0, 0);
                acc = __builtin_amdgcn_mfma_f32_16x16x32_bf16(Am0, Xhi[tt][0], acc, 0, 0, 0);
                acc = __builtin_amdgcn_mfma_f32_16x16x32_bf16(Am1, Xhi[tt][1], acc, 0, 0, 0);
#pragma unroll
                for (int rr = 0; rr < 4; ++rr) {
                    float d = fmaf(-2.f, acc[rr], bqv[rr]);
                    bool lt = d < best[tt][rr];
                    sec[tt][rr] = __builtin_amdgcn_fmed3f(d, best[tt][rr], sec[tt][rr]);
                    best[tt][rr] = fminf(best[tt][rr], d);
                    bbase[tt][rr] = lt ? bv : bbase[tt][rr];
                }
            }
        }
        __syncthreads();
        if (t + 4 < 64) {
            smem[0][woff] = r0; smem[1][woff] = r1;
            smem[2][woff] = r2; smem[3][woff] = r3;
        }
        __syncthreads();
    }

#pragma unroll
    for (int tt = 0; tt < 4; ++tt) {
        float b = best[tt][0], s2 = sec[tt][0];
        int bi = bbase[tt][0];
#pragma unroll
        for (int rr = 1; rr < 4; ++rr) {
            float ob = best[tt][rr];
            int oi = bbase[tt][rr] + rr;
            s2 = fminf(fminf(s2, sec[tt][rr]), fmaxf(b, ob));
            bool lt2 = (ob < b) || (ob == b && oi < bi);
            b = lt2 ? ob : b; bi = lt2 ? oi : bi;
        }
#pragma unroll
        for (int off = 16; off <= 32; off <<= 1) {
            float ob = __shfl_xor(b, off, 64);
            float os = __shfl_xor(s2, off, 64);
            int   oi = __shfl_xor(bi, off, 64);
            s2 = fminf(fminf(s2, os), fmaxf(b, ob));
            bool lt = (ob < b) || (ob == b && oi < bi);
            b = lt ? ob : b; bi = lt ? oi : bi;
        }
        if (lane < 16) {
            int token = tokb + tt * 16 + lane;
            out[IDXOFF + token] = (float)bi;
            idxs[wv * 64 + tt * 16 + lane] = bi;
            if (s2 - b < MARGIN) {
                int pos = atomicAdd((int*)ws + OFF_RCNT, 1);
                if (pos < RCAP) ((int*)ws)[OFF_RLIST + pos] = token;
            }
        }
    }
    __syncthreads();

    // fused quantized + loss epilogue (refine corrects flagged rows later)
    float se = 0.f;
    int tokb0 = blockIdx.x * 256;
#pragma unroll
    for (int i = 0; i < 16; ++i) {
        int gi = i * 256 + tid;
        int tok = gi >> 4, qd = gi & 15;
        int ci = idxs[tok];
        float4 xvv = *(const float4*)(x + (size_t)(tokb0 + tok) * 64 + qd * 4);
        float4 qv = *(const float4*)(cbf + (size_t)ci * 64 + qd * 4);
        float d0 = qv.x - xvv.x, d1 = qv.y - xvv.y;
        float d2 = qv.z - xvv.z, d3 = qv.w - xvv.w;
        float4 o;
        o.x = xvv.x + d0; o.y = xvv.y + d1; o.z = xvv.z + d2; o.w = xvv.w + d3;
        *(float4*)(out + (size_t)(tokb0 + tok) * 64 + qd * 4) = o;
        se += d0 * d0 + d1 * d1 + d2 * d2 + d3 * d3;
    }
    for (int off = 32; off; off >>= 1) se += __shfl_down(se, off, 64);
    if (lane == 0) red[wv] = se;
    __syncthreads();
    if (tid == 0) ws[OFF_BLK + blockIdx.x] = (red[0] + red[1]) + (red[2] + red[3]);
}

// exact fp32 re-scan for flagged tokens; fixes quantized rows + loss delta.
__global__ __launch_bounds__(256) void vq_refine(const float* __restrict__ x,
                                                 const float* __restrict__ cb,
                                                 float* __restrict__ out,
                                                 float* __restrict__ ws) {
    __shared__ float ctile[128][64];               // 32KB
    __shared__ float xs[8][64];
    __shared__ float As[8];
    __shared__ int   tokid[8], oidx[8], nidx[8];
    __shared__ unsigned long long rkeys[8][128];   // 8KB
    __shared__ float dred[4];

    int cnt = min(((int*)ws)[OFF_RCNT], RCAP);
    if (cnt <= 0) return;
    int ngroups = (cnt + 7) >> 3;
    int tid = threadIdx.x;
    int code = tid & 127, th = tid >> 7;

    for (int grp = blockIdx.x; grp < ngroups; grp += gridDim.x) {
        if (tid < 8) {
            int i = grp * 8 + tid;
            int t = ((int*)ws)[OFF_RLIST + min(i, cnt - 1)];
            tokid[tid] = t;
            oidx[tid] = (int)out[IDXOFF + t];
        }
        __syncthreads();
#pragma unroll
        for (int it = 0; it < 2; ++it) {
            int idx = it * 256 + tid;
            xs[idx >> 6][idx & 63] = x[(size_t)tokid[idx >> 6] * 64 + (idx & 63)];
        }
        __syncthreads();
        if (tid < 8) {   // exact R2 A-chain
            float a0 = 0.f, a1 = 0.f, a2 = 0.f, a3 = 0.f;
#pragma unroll
            for (int kc = 0; kc < 16; ++kc) {
                float4 xk = *(const float4*)(xs[tid] + kc * 4);
                a0 = fmaf(xk.x, xk.x, a0); a1 = fmaf(xk.y, xk.y, a1);
                a2 = fmaf(xk.z, xk.z, a2); a3 = fmaf(xk.w, xk.w, a3);
            }
            As[tid] = (a0 + a1) + (a2 + a3);
        }

        unsigned long long bk[4] = {~0ull, ~0ull, ~0ull, ~0ull};
        int tb = th * 4;

        for (int pass = 0; pass < 8; ++pass) {
            int cbase = pass * 128;
            __syncthreads();
#pragma unroll
            for (int it = 0; it < 8; ++it) {
                int gi = it * 256 + tid;
                int cc = gi >> 4, qq = gi & 15;
                float4 v = *(const float4*)(cb + (size_t)(cbase + cc) * 64 + qq * 4);
                *(float4*)&ctile[cc][(qq ^ (cc & 15)) * 4] = v;
            }
            __syncthreads();

            float p0 = 0.f, p1 = 0.f, p2 = 0.f, p3 = 0.f;
#pragma unroll
            for (int qq = 0; qq < 16; ++qq) {
                float4 cv = *(const float4*)&ctile[code][(qq ^ (code & 15)) * 4];
                float4 x0 = *(const float4*)(xs[tb + 0] + qq * 4);
                float4 x1 = *(const float4*)(xs[tb + 1] + qq * 4);
                float4 x2 = *(const float4*)(xs[tb + 2] + qq * 4);
                float4 x3 = *(const float4*)(xs[tb + 3] + qq * 4);
                p0 = fmaf(x0.x, cv.x, p0); p0 = fmaf(x0.y, cv.y, p0);
                p0 = fmaf(x0.z, cv.z, p0); p0 = fmaf(x0.w, cv.w, p0);
                p1 = fmaf(x1.x, cv.x, p1); p1 = fmaf(x1.y, cv.y, p1);
                p1 = fmaf(x1.z, cv.z, p1); p1 = fmaf(x1.w, cv.w, p1);
                p2 = fmaf(x2.x, cv.x, p2); p2 = fmaf(x2.y, cv.y, p2);
                p2 = fmaf(x2.z, cv.z, p2); p2 = fmaf(x2.w, cv.w, p2);
                p3 = fmaf(x3.x, cv.x, p3); p3 = fmaf(x3.y, cv.y, p3);
                p3 = fmaf(x3.z, cv.z, p3); p3 = fmaf(x3.w, cv.w, p3);
            }
            float bn = ws[OFF_BC + cbase + code];
            int gcode = cbase + code;
            float pv[4] = {p0, p1, p2, p3};
#pragma unroll
            for (int j = 0; j < 4; ++j) {
                float s = As[tb + j] + bn;
                float d = fmaf(-2.0f, pv[j], s);   // == fl(s - 2p)
                unsigned long long key =
                    (((unsigned long long)__float_as_uint(d)) << 32) | (unsigned)gcode;
                bk[j] = min(bk[j], key);
            }
        }
        __syncthreads();
#pragma unroll
        for (int j = 0; j < 4; ++j) rkeys[tb + j][code] = bk[j];
        __syncthreads();

        int wv2 = tid >> 6, lane = tid & 63;
#pragma unroll
        for (int u = 0; u < 2; ++u) {
            int tt = wv2 * 2 + u;
            unsigned long long k = min(rkeys[tt][lane], rkeys[tt][lane + 64]);
#pragma unroll
            for (int off = 32; off; off >>= 1)
                k = min(k, (unsigned long long)__shfl_xor((long long)k, off, 64));
            if (lane == 0) {
                int ni = (int)(unsigned)(k & 0xffffffffull);
                nidx[tt] = ni;
                if (grp * 8 + tt < cnt) out[IDXOFF + tokid[tt]] = (float)ni;
            }
        }
        __syncthreads();

        float delta = 0.f;
        {
            int tok = tid >> 5, e2 = (tid & 31) * 2;
            if (grp * 8 + tok < cnt) {
                int nw = nidx[tok], od = oidx[tok];
                if (nw != od) {
                    float x0 = xs[tok][e2], x1 = xs[tok][e2 + 1];
                    float qn0 = cb[(size_t)nw * 64 + e2], qn1 = cb[(size_t)nw * 64 + e2 + 1];
                    float qo0 = cb[(size_t)od * 64 + e2], qo1 = cb[(size_t)od * 64 + e2 + 1];
                    float dn0 = qn0 - x0, dn1 = qn1 - x1;
                    float do0 = qo0 - x0, do1 = qo1 - x1;
                    out[(size_t)tokid[tok] * 64 + e2]     = x0 + dn0;
                    out[(size_t)tokid[tok] * 64 + e2 + 1] = x1 + dn1;
                    delta = (dn0 * dn0 + dn1 * dn1) - (do0 * do0 + do1 * do1);
                }
            }
        }
        for (int off = 32; off; off >>= 1) delta += __shfl_down(delta, off, 64);
        if ((tid & 63) == 0) dred[tid >> 6] = delta;
        __syncthreads();
        if (tid == 0) {
            float dsum = (dred[0] + dred[1]) + (dred[2] + dred[3]);
            if (dsum != 0.f) atomicAdd(ws + OFF_CORR, dsum);
        }
        __syncthreads();
    }
}

__global__ __launch_bounds__(256) void vq_loss2(float* __restrict__ out,
                                                const float* __restrict__ ws) {
    const float* blk = ws + OFF_BLK;
    __shared__ double sd[256];
    double s = 0.0;
    for (int i = threadIdx.x; i < 1024; i += 256) s += (double)blk[i];
    sd[threadIdx.x] = s;
    __syncthreads();
    for (int off = 128; off; off >>= 1) {
        if (threadIdx.x < off) sd[threadIdx.x] += sd[threadIdx.x + off];
        __syncthreads();
    }
    if (threadIdx.x == 0) {
        double tot = sd[0] + (double)ws[OFF_CORR];
        out[LOSSOFF] = (float)(1.25 * tot / ((double)NTOK * (double)DIM));
    }
}

extern "C" void kernel_launch(void* const* d_in, const int* in_sizes, int n_in,
                              void* d_out, int out_size, void* d_ws, size_t ws_size,
                              hipStream_t stream) {
    (void)in_sizes; (void)n_in; (void)out_size; (void)ws_size;
    const float* x = (const float*)d_in[0];
    const float* cb = (const float*)d_in[1];
    float* out = (float*)d_out;
    float* ws = (float*)d_ws;

    hipLaunchKernelGGL(vq_prep_cb, dim3(4), dim3(256), 0, stream, cb, ws);
    hipLaunchKernelGGL(vq_mfma, dim3(1024), dim3(256), 0, stream, x, cb, out, ws);
    hipLaunchKernelGGL(vq_refine, dim3(1024), dim3(256), 0, stream, x, cb, out, ws);
    hipLaunchKernelGGL(vq_loss2, dim3(1), dim3(256), 0, stream, out, ws);
}

// Round 15
// 245.592 us; speedup vs baseline: 1.1475x; 1.0279x over previous
//
#include <hip/hip_runtime.h>
#include <math.h>

#define NTOK   262144
#define DIM    64
#define NCODE  1024
#define LOSSOFF (NTOK*DIM)          // 16777216
#define IDXOFF  (NTOK*DIM + 1)

#define MARGIN 1e-4f
#define RCAP   65536
#define NBLK   256

// ws float-offsets
#define OFF_BC     0               // 1024 f
#define OFF_CBHI   1024            // ushort[65536] = 32768 f
#define OFF_CBMID  33792           // 32768 f
#define OFF_RCNT   66560           // 1 int
#define OFF_CORR   66561           // 1 float
#define OFF_RLIST  66562           // 65536 int
#define OFF_BLK    132098          // 256 f
#define WS_FLOATS  132354

typedef __attribute__((ext_vector_type(8))) short short8;
typedef __attribute__((ext_vector_type(4))) float f32x4;

__device__ __forceinline__ ushort bf16rn(float f) {
    unsigned u = __float_as_uint(f);
    return (ushort)((u + 0x7fffu + ((u >> 16) & 1u)) >> 16);
}
__device__ __forceinline__ float bf16tof(ushort h) {
    return __uint_as_float(((unsigned)h) << 16);
}

__global__ __launch_bounds__(256) void vq_prep_cb(const float* __restrict__ cb,
                                                  float* __restrict__ ws) {
    int c = blockIdx.x * 256 + threadIdx.x;
    if (c == 0) { ((int*)ws)[OFF_RCNT] = 0; ws[OFF_CORR] = 0.f; }
    if (c >= NCODE) return;
    ushort* cbh = (ushort*)(ws + OFF_CBHI);
    ushort* cbm = (ushort*)(ws + OFF_CBMID);
    const float4* p = (const float4*)(cb + (size_t)c * DIM);
    float a0 = 0.f, a1 = 0.f, a2 = 0.f, a3 = 0.f;
#pragma unroll
    for (int i = 0; i < 16; i++) {
        float4 v = p[i];
        a0 = fmaf(v.x, v.x, a0); a1 = fmaf(v.y, v.y, a1);
        a2 = fmaf(v.z, v.z, a2); a3 = fmaf(v.w, v.w, a3);
        ushort4 h, m;
        h.x = bf16rn(v.x); m.x = bf16rn(v.x - bf16tof(h.x));
        h.y = bf16rn(v.y); m.y = bf16rn(v.y - bf16tof(h.y));
        h.z = bf16rn(v.z); m.z = bf16rn(v.z - bf16tof(h.z));
        h.w = bf16rn(v.w); m.w = bf16rn(v.w - bf16tof(h.w));
        ((ushort4*)(cbh + (size_t)c * 64))[i] = h;
        ((ushort4*)(cbm + (size_t)c * 64))[i] = m;
    }
    ws[OFF_BC + c] = (a0 + a1) + (a2 + a3);   // exact R2 prep chain
}

// Codebook-resident persistent scan: 1 block/CU (128KB LDS holds 512 codes'
// hi+mid splits), 8 waves, 1024 tokens/block in 4 sweeps. Barriers only
// around the 5 half-codebook refills; scan loops are barrier-free so waves
// overlap MFMA/LDS/VALU pipes. Distances bit-identical to R12.
__global__ __launch_bounds__(512)
__attribute__((amdgpu_waves_per_eu(2, 2)))
void vq_scan(const float* __restrict__ x,
             const float* __restrict__ cbf,
             float* __restrict__ out,
             float* __restrict__ ws) {
    __shared__ uint4 lds[8192];     // 512 rows x 16 slots (8 hi + 8 mid) = 128KB
    __shared__ float red[8];
    const float* Bc = ws + OFF_BC;
    const ushort* cbh = (const ushort*)(ws + OFF_CBHI);
    const ushort* cbm = (const ushort*)(ws + OFF_CBMID);

    int tid = threadIdx.x, lane = tid & 63, wv = tid >> 6;
    int col = lane & 15, q = lane >> 4, q4 = q * 4;
    int cx7 = col & 7;
    int s_h0 = q ^ cx7, s_h1 = (4 + q) ^ cx7;
    int s_m0 = 8 + s_h0, s_m1 = 8 + s_h1;

    float se_tot = 0.f;

    for (int sweep = 0; sweep < 4; ++sweep) {
        int tokb = blockIdx.x * 1024 + sweep * 256 + wv * 32;

        float4 xr4[2][4];
        short8 Xhi[2][2], Xmid[2][2];
#pragma unroll
        for (int tt = 0; tt < 2; ++tt) {
            const float* xr = x + (size_t)(tokb + tt * 16 + col) * 64;
#pragma unroll
            for (int s = 0; s < 2; ++s) {
                float4 v0 = *(const float4*)(xr + s * 32 + q * 8);
                float4 v1 = *(const float4*)(xr + s * 32 + q * 8 + 4);
                xr4[tt][s * 2] = v0; xr4[tt][s * 2 + 1] = v1;
                float vv[8] = {v0.x, v0.y, v0.z, v0.w, v1.x, v1.y, v1.z, v1.w};
                short8 hv, mv;
#pragma unroll
                for (int j = 0; j < 8; ++j) {
                    ushort h = bf16rn(vv[j]);
                    float r = vv[j] - bf16tof(h);   // exact (Sterbenz)
                    hv[j] = (short)h; mv[j] = (short)bf16rn(r);
                }
                Xhi[tt][s] = hv; Xmid[tt][s] = mv;
            }
        }

        float best0[2][4], sec0[2][4], best1[2][4], sec1[2][4];
        int base0[2][4], base1[2][4];
#pragma unroll
        for (int tt = 0; tt < 2; ++tt)
#pragma unroll
            for (int rr = 0; rr < 4; ++rr) {
                best0[tt][rr] = 3.4e38f; sec0[tt][rr] = 3.4e38f; base0[tt][rr] = 0;
                best1[tt][rr] = 3.4e38f; sec1[tt][rr] = 3.4e38f; base1[tt][rr] = 0;
            }

        // scan one resident half; dofill/half are block-uniform at each call
        auto scan_half = [&](float (&bt)[2][4], float (&sc)[2][4], int (&bb)[2][4],
                             int half, bool dofill) __attribute__((always_inline)) {
            if (dofill) {
                __syncthreads();   // protect prior scans of the buffer
                const ushort* hs = cbh + (size_t)(half * 512 + tid) * 64;
                const ushort* ms = cbm + (size_t)(half * 512 + tid) * 64;
                uint4* row = lds + tid * 16;
                int sw = tid & 7;
#pragma unroll
                for (int g = 0; g < 8; ++g) {
                    row[g ^ sw]       = *(const uint4*)(hs + g * 8);
                    row[8 + (g ^ sw)] = *(const uint4*)(ms + g * 8);
                }
                __syncthreads();
            }
            int cb0 = half * 512;
#pragma unroll 4
            for (int t = 0; t < 32; ++t) {
                const uint4* row = lds + (t * 16 + col) * 16;
                short8 Ah0 = __builtin_bit_cast(short8, row[s_h0]);
                short8 Ah1 = __builtin_bit_cast(short8, row[s_h1]);
                short8 Am0 = __builtin_bit_cast(short8, row[s_m0]);
                short8 Am1 = __builtin_bit_cast(short8, row[s_m1]);
                float4 bq = *(const float4*)(Bc + cb0 + t * 16 + q4);
                int bv = cb0 + t * 16 + q4;
                float bqv[4] = {bq.x, bq.y, bq.z, bq.w};
#pragma unroll
                for (int tt = 0; tt < 2; ++tt) {
                    f32x4 acc = {0.f, 0.f, 0.f, 0.f};
                    acc = __builtin_amdgcn_mfma_f32_16x16x32_bf16(Ah0, Xhi[tt][0], acc, 0, 0, 0);
                    acc = __builtin_amdgcn_mfma_f32_16x16x32_bf16(Ah1, Xhi[tt][1], acc, 0, 0, 0);
                    acc = __builtin_amdgcn_mfma_f32_16x16x32_bf16(Ah0, Xmid[tt][0], acc, 0, 0, 0);
                    acc = __builtin_amdgcn_mfma_f32_16x16x32_bf16(Ah1, Xmid[tt][1], acc, 0, 0, 0);
                    acc = __builtin_amdgcn_mfma_f32_16x16x32_bf16(Am0, Xhi[tt][0], acc, 0, 0, 0);
                    acc = __builtin_amdgcn_mfma_f32_16x16x32_bf16(Am1, Xhi[tt][1], acc, 0, 0, 0);
#pragma unroll
                    for (int rr = 0; rr < 4; ++rr) {
                        float d = fmaf(-2.f, acc[rr], bqv[rr]);
                        bool lt = d < bt[tt][rr];
                        sc[tt][rr] = __builtin_amdgcn_fmed3f(d, bt[tt][rr], sc[tt][rr]);
                        bt[tt][rr] = fminf(bt[tt][rr], d);
                        bb[tt][rr] = lt ? bv : bb[tt][rr];
                    }
                }
            }
        };

        if ((sweep & 1) == 0) {
            scan_half(best0, sec0, base0, 0, sweep == 0);
            scan_half(best1, sec1, base1, 1, true);
        } else {
            scan_half(best1, sec1, base1, 1, false);   // resident from prev sweep
            scan_half(best0, sec0, base0, 0, true);
        }

        // merge 16 slots (half0 then half1: code-ascending -> first-min ties)
#pragma unroll
        for (int tt = 0; tt < 2; ++tt) {
            float b = best0[tt][0], s2 = sec0[tt][0];
            int bi = base0[tt][0];
#pragma unroll
            for (int rr = 1; rr < 4; ++rr) {
                float ob = best0[tt][rr]; int oi = base0[tt][rr] + rr;
                s2 = fminf(fminf(s2, sec0[tt][rr]), fmaxf(b, ob));
                bool lt = (ob < b) || (ob == b && oi < bi);
                b = lt ? ob : b; bi = lt ? oi : bi;
            }
#pragma unroll
            for (int rr = 0; rr < 4; ++rr) {
                float ob = best1[tt][rr]; int oi = base1[tt][rr] + rr;
                s2 = fminf(fminf(s2, sec1[tt][rr]), fmaxf(b, ob));
                bool lt = (ob < b) || (ob == b && oi < bi);
                b = lt ? ob : b; bi = lt ? oi : bi;
            }
#pragma unroll
            for (int off = 16; off <= 32; off <<= 1) {
                float ob = __shfl_xor(b, off, 64);
                float os = __shfl_xor(s2, off, 64);
                int   oi = __shfl_xor(bi, off, 64);
                s2 = fminf(fminf(s2, os), fmaxf(b, ob));
                bool lt = (ob < b) || (ob == b && oi < bi);
                b = lt ? ob : b; bi = lt ? oi : bi;
            }
            int token = tokb + tt * 16 + col;
            if (lane < 16) {
                out[IDXOFF + token] = (float)bi;
                if (s2 - b < MARGIN) {
                    int pos = atomicAdd((int*)ws + OFF_RCNT, 1);
                    if (pos < RCAP) ((int*)ws)[OFF_RLIST + pos] = token;
                }
            }
            // quantized + loss epilogue: this lane owns exactly the x elements
            // it loaded (granules q and 4+q) -> no x re-read, no LDS, no barrier
            const float* qrow = cbf + (size_t)bi * 64;
            float* orow = out + (size_t)token * 64;
#pragma unroll
            for (int s = 0; s < 2; ++s) {
                float4 qv0 = *(const float4*)(qrow + s * 32 + q * 8);
                float4 qv1 = *(const float4*)(qrow + s * 32 + q * 8 + 4);
                float4 xv0 = xr4[tt][s * 2], xv1 = xr4[tt][s * 2 + 1];
                float d0 = qv0.x - xv0.x, d1 = qv0.y - xv0.y;
                float d2 = qv0.z - xv0.z, d3 = qv0.w - xv0.w;
                float e0 = qv1.x - xv1.x, e1 = qv1.y - xv1.y;
                float e2 = qv1.z - xv1.z, e3 = qv1.w - xv1.w;
                float4 o0, o1;
                o0.x = xv0.x + d0; o0.y = xv0.y + d1; o0.z = xv0.z + d2; o0.w = xv0.w + d3;
                o1.x = xv1.x + e0; o1.y = xv1.y + e1; o1.z = xv1.z + e2; o1.w = xv1.w + e3;
                *(float4*)(orow + s * 32 + q * 8) = o0;
                *(float4*)(orow + s * 32 + q * 8 + 4) = o1;
                se_tot += d0 * d0 + d1 * d1 + d2 * d2 + d3 * d3;
                se_tot += e0 * e0 + e1 * e1 + e2 * e2 + e3 * e3;
            }
        }
    }

    for (int off = 32; off; off >>= 1) se_tot += __shfl_down(se_tot, off, 64);
    if (lane == 0) red[wv] = se_tot;
    __syncthreads();
    if (tid == 0) {
        float s = 0.f;
#pragma unroll
        for (int i = 0; i < 8; ++i) s += red[i];
        ws[OFF_BLK + blockIdx.x] = s;
    }
}

// exact fp32 re-scan for flagged tokens; fixes quantized rows + loss delta.
__global__ __launch_bounds__(256) void vq_refine(const float* __restrict__ x,
                                                 const float* __restrict__ cb,
                                                 float* __restrict__ out,
                                                 float* __restrict__ ws) {
    __shared__ float ctile[128][64];               // 32KB
    __shared__ float xs[8][64];
    __shared__ float As[8];
    __shared__ int   tokid[8], oidx[8], nidx[8];
    __shared__ unsigned long long rkeys[8][128];   // 8KB
    __shared__ float dred[4];

    int cnt = min(((int*)ws)[OFF_RCNT], RCAP);
    if (cnt <= 0) return;
    int ngroups = (cnt + 7) >> 3;
    int tid = threadIdx.x;
    int code = tid & 127, th = tid >> 7;

    for (int grp = blockIdx.x; grp < ngroups; grp += gridDim.x) {
        if (tid < 8) {
            int i = grp * 8 + tid;
            int t = ((int*)ws)[OFF_RLIST + min(i, cnt - 1)];
            tokid[tid] = t;
            oidx[tid] = (int)out[IDXOFF + t];
        }
        __syncthreads();
#pragma unroll
        for (int it = 0; it < 2; ++it) {
            int idx = it * 256 + tid;
            xs[idx >> 6][idx & 63] = x[(size_t)tokid[idx >> 6] * 64 + (idx & 63)];
        }
        __syncthreads();
        if (tid < 8) {   // exact R2 A-chain
            float a0 = 0.f, a1 = 0.f, a2 = 0.f, a3 = 0.f;
#pragma unroll
            for (int kc = 0; kc < 16; ++kc) {
                float4 xk = *(const float4*)(xs[tid] + kc * 4);
                a0 = fmaf(xk.x, xk.x, a0); a1 = fmaf(xk.y, xk.y, a1);
                a2 = fmaf(xk.z, xk.z, a2); a3 = fmaf(xk.w, xk.w, a3);
            }
            As[tid] = (a0 + a1) + (a2 + a3);
        }

        unsigned long long bk[4] = {~0ull, ~0ull, ~0ull, ~0ull};
        int tb = th * 4;

        for (int pass = 0; pass < 8; ++pass) {
            int cbase = pass * 128;
            __syncthreads();
#pragma unroll
            for (int it = 0; it < 8; ++it) {
                int gi = it * 256 + tid;
                int cc = gi >> 4, qq = gi & 15;
                float4 v = *(const float4*)(cb + (size_t)(cbase + cc) * 64 + qq * 4);
                *(float4*)&ctile[cc][(qq ^ (cc & 15)) * 4] = v;
            }
            __syncthreads();

            float p0 = 0.f, p1 = 0.f, p2 = 0.f, p3 = 0.f;
#pragma unroll
            for (int qq = 0; qq < 16; ++qq) {
                float4 cv = *(const float4*)&ctile[code][(qq ^ (code & 15)) * 4];
                float4 x0 = *(const float4*)(xs[tb + 0] + qq * 4);
                float4 x1 = *(const float4*)(xs[tb + 1] + qq * 4);
                float4 x2 = *(const float4*)(xs[tb + 2] + qq * 4);
                float4 x3 = *(const float4*)(xs[tb + 3] + qq * 4);
                p0 = fmaf(x0.x, cv.x, p0); p0 = fmaf(x0.y, cv.y, p0);
                p0 = fmaf(x0.z, cv.z, p0); p0 = fmaf(x0.w, cv.w, p0);
                p1 = fmaf(x1.x, cv.x, p1); p1 = fmaf(x1.y, cv.y, p1);
                p1 = fmaf(x1.z, cv.z, p1); p1 = fmaf(x1.w, cv.w, p1);
                p2 = fmaf(x2.x, cv.x, p2); p2 = fmaf(x2.y, cv.y, p2);
                p2 = fmaf(x2.z, cv.z, p2); p2 = fmaf(x2.w, cv.w, p2);
                p3 = fmaf(x3.x, cv.x, p3); p3 = fmaf(x3.y, cv.y, p3);
                p3 = fmaf(x3.z, cv.z, p3); p3 = fmaf(x3.w, cv.w, p3);
            }
            float bn = ws[OFF_BC + cbase + code];
            int gcode = cbase + code;
            float pv[4] = {p0, p1, p2, p3};
#pragma unroll
            for (int j = 0; j < 4; ++j) {
                float s = As[tb + j] + bn;
                float d = fmaf(-2.0f, pv[j], s);   // == fl(s - 2p)
                unsigned long long key =
                    (((unsigned long long)__float_as_uint(d)) << 32) | (unsigned)gcode;
                bk[j] = min(bk[j], key);
            }
        }
        __syncthreads();
#pragma unroll
        for (int j = 0; j < 4; ++j) rkeys[tb + j][code] = bk[j];
        __syncthreads();

        int wv2 = tid >> 6, lane = tid & 63;
#pragma unroll
        for (int u = 0; u < 2; ++u) {
            int tt = wv2 * 2 + u;
            unsigned long long k = min(rkeys[tt][lane], rkeys[tt][lane + 64]);
#pragma unroll
            for (int off = 32; off; off >>= 1)
                k = min(k, (unsigned long long)__shfl_xor((long long)k, off, 64));
            if (lane == 0) {
                int ni = (int)(unsigned)(k & 0xffffffffull);
                nidx[tt] = ni;
                if (grp * 8 + tt < cnt) out[IDXOFF + tokid[tt]] = (float)ni;
            }
        }
        __syncthreads();

        float delta = 0.f;
        {
            int tok = tid >> 5, e2 = (tid & 31) * 2;
            if (grp * 8 + tok < cnt) {
                int nw = nidx[tok], od = oidx[tok];
                if (nw != od) {
                    float x0 = xs[tok][e2], x1 = xs[tok][e2 + 1];
                    float qn0 = cb[(size_t)nw * 64 + e2], qn1 = cb[(size_t)nw * 64 + e2 + 1];
                    float qo0 = cb[(size_t)od * 64 + e2], qo1 = cb[(size_t)od * 64 + e2 + 1];
                    float dn0 = qn0 - x0, dn1 = qn1 - x1;
                    float do0 = qo0 - x0, do1 = qo1 - x1;
                    out[(size_t)tokid[tok] * 64 + e2]     = x0 + dn0;
                    out[(size_t)tokid[tok] * 64 + e2 + 1] = x1 + dn1;
                    delta = (dn0 * dn0 + dn1 * dn1) - (do0 * do0 + do1 * do1);
                }
            }
        }
        for (int off = 32; off; off >>= 1) delta += __shfl_down(delta, off, 64);
        if ((tid & 63) == 0) dred[tid >> 6] = delta;
        __syncthreads();
        if (tid == 0) {
            float dsum = (dred[0] + dred[1]) + (dred[2] + dred[3]);
            if (dsum != 0.f) atomicAdd(ws + OFF_CORR, dsum);
        }
        __syncthreads();
    }
}

__global__ __launch_bounds__(256) void vq_loss2(float* __restrict__ out,
                                                const float* __restrict__ ws) {
    const float* blk = ws + OFF_BLK;
    __shared__ double sd[256];
    double s = (double)blk[threadIdx.x];
    sd[threadIdx.x] = s;
    __syncthreads();
    for (int off = 128; off; off >>= 1) {
        if (threadIdx.x < off) sd[threadIdx.x] += sd[threadIdx.x + off];
        __syncthreads();
    }
    if (threadIdx.x == 0) {
        double tot = sd[0] + (double)ws[OFF_CORR];
        out[LOSSOFF] = (float)(1.25 * tot / ((double)NTOK * (double)DIM));
    }
}

extern "C" void kernel_launch(void* const* d_in, const int* in_sizes, int n_in,
                              void* d_out, int out_size, void* d_ws, size_t ws_size,
                              hipStream_t stream) {
    (void)in_sizes; (void)n_in; (void)out_size; (void)ws_size;
    const float* x = (const float*)d_in[0];
    const float* cb = (const float*)d_in[1];
    float* out = (float*)d_out;
    float* ws = (float*)d_ws;

    hipLaunchKernelGGL(vq_prep_cb, dim3(4), dim3(256), 0, stream, cb, ws);
    hipLaunchKernelGGL(vq_scan, dim3(NBLK), dim3(512), 0, stream, x, cb, out, ws);
    hipLaunchKernelGGL(vq_refine, dim3(1024), dim3(256), 0, stream, x, cb, out, ws);
    hipLaunchKernelGGL(vq_loss2, dim3(1), dim3(256), 0, stream, out, ws);
}

// Round 16
// 197.832 us; speedup vs baseline: 1.4245x; 1.2414x over previous
//
#include <hip/hip_runtime.h>
#include <math.h>

#define NTOK   262144
#define DIM    64
#define NCODE  1024
#define LOSSOFF (NTOK*DIM)          // 16777216
#define IDXOFF  (NTOK*DIM + 1)

#define MARGIN 1e-4f
#define RCAP   65536

// ws float-offsets
#define OFF_BC     0               // 1024 f
#define OFF_CBHI   1024            // ushort[65536] = 32768 f
#define OFF_CBMID  33792           // 32768 f
#define OFF_RCNT   66560           // 1 int
#define OFF_CORR   66561           // 1 float
#define OFF_RLIST  66562           // 65536 int
#define OFF_BLK    132098          // 2048 f
#define WS_FLOATS  134146

typedef __attribute__((ext_vector_type(8))) short short8;
typedef __attribute__((ext_vector_type(4))) float f32x4;

__device__ __forceinline__ ushort bf16rn(float f) {
    unsigned u = __float_as_uint(f);
    return (ushort)((u + 0x7fffu + ((u >> 16) & 1u)) >> 16);
}
__device__ __forceinline__ float bf16tof(ushort h) {
    return __uint_as_float(((unsigned)h) << 16);
}

__global__ __launch_bounds__(256) void vq_prep_cb(const float* __restrict__ cb,
                                                  float* __restrict__ ws) {
    int c = blockIdx.x * 256 + threadIdx.x;
    if (c == 0) { ((int*)ws)[OFF_RCNT] = 0; ws[OFF_CORR] = 0.f; }
    if (c >= NCODE) return;
    ushort* cbh = (ushort*)(ws + OFF_CBHI);
    ushort* cbm = (ushort*)(ws + OFF_CBMID);
    const float4* p = (const float4*)(cb + (size_t)c * DIM);
    float a0 = 0.f, a1 = 0.f, a2 = 0.f, a3 = 0.f;
#pragma unroll
    for (int i = 0; i < 16; i++) {
        float4 v = p[i];
        a0 = fmaf(v.x, v.x, a0); a1 = fmaf(v.y, v.y, a1);
        a2 = fmaf(v.z, v.z, a2); a3 = fmaf(v.w, v.w, a3);
        ushort4 h, m;
        h.x = bf16rn(v.x); m.x = bf16rn(v.x - bf16tof(h.x));
        h.y = bf16rn(v.y); m.y = bf16rn(v.y - bf16tof(h.y));
        h.z = bf16rn(v.z); m.z = bf16rn(v.z - bf16tof(h.z));
        h.w = bf16rn(v.w); m.w = bf16rn(v.w - bf16tof(h.w));
        ((ushort4*)(cbh + (size_t)c * 64))[i] = h;
        ((ushort4*)(cbm + (size_t)c * 64))[i] = m;
    }
    ws[OFF_BC + c] = (a0 + a1) + (a2 + a3);   // exact R2 prep chain
}

// R12 champion + single-barrier ping-pong: two 4-buffer LDS sets; round r
// computes tiles 4r..4r+3 from set(r&1) while ds_writing tiles of round r+1
// into the other set (regs loaded one full round earlier -> vmcnt slack).
// ONE __syncthreads per round (was 2). waves_per_eu(3) caps unified regs at
// 170/wave -> >=3 waves/SIMD (R12 measured ~20% occupancy: AGPR homing).
// Distances bit-identical to R12 (same swizzle, same 6-MFMA chain).
__global__ __launch_bounds__(256)
__attribute__((amdgpu_waves_per_eu(3)))
void vq_mfma(const float* __restrict__ x,
             const float* __restrict__ cbf,
             float* __restrict__ out,
             float* __restrict__ ws) {
    __shared__ uint4 smem[8][256];   // 32KB: sets [0..3] / [4..7]
    __shared__ int idxs[128];
    __shared__ float red[4];
    const float* Bc = ws + OFF_BC;
    const ushort* cbh = (const ushort*)(ws + OFF_CBHI);
    const ushort* cbm = (const ushort*)(ws + OFF_CBMID);

    int tid = threadIdx.x, lane = tid & 63, wv = tid >> 6;
    int col = lane & 15, q = lane >> 4, q4 = q * 4;
    int tokb = blockIdx.x * 128 + wv * 32;

    short8 Xhi[2][2], Xmid[2][2];
#pragma unroll
    for (int tt = 0; tt < 2; ++tt) {
        int token = tokb + tt * 16 + col;
        const float* xr = x + (size_t)token * 64;
#pragma unroll
        for (int s = 0; s < 2; ++s) {
            float4 v0 = *(const float4*)(xr + s * 32 + q * 8);
            float4 v1 = *(const float4*)(xr + s * 32 + q * 8 + 4);
            float vv[8] = {v0.x, v0.y, v0.z, v0.w, v1.x, v1.y, v1.z, v1.w};
            short8 hv, mv;
#pragma unroll
            for (int j = 0; j < 8; ++j) {
                ushort h = bf16rn(vv[j]);
                float r = vv[j] - bf16tof(h);   // exact (Sterbenz)
                hv[j] = (short)h; mv[j] = (short)bf16rn(r);
            }
            Xhi[tt][s] = hv; Xmid[tt][s] = mv;
        }
    }

    float best[2][4], sec[2][4];
    int bbase[2][4];
#pragma unroll
    for (int tt = 0; tt < 2; ++tt)
#pragma unroll
        for (int rr = 0; rr < 4; ++rr) {
            best[tt][rr] = 3.4e38f; sec[tt][rr] = 3.4e38f; bbase[tt][rr] = 0;
        }

    int chunk = tid >> 7, e = tid & 127, scode = e >> 3, g = e & 7;
    const ushort* sb0 = (chunk ? cbm : cbh) + (size_t)scode * 64 + g * 8;
    int woff = chunk * 128 + scode * 8 + (g ^ (scode & 7));
    int ro_h0 = col * 8 + ((0 + q) ^ (col & 7));
    int ro_h1 = col * 8 + ((4 + q) ^ (col & 7));
    int ro_m0 = 128 + col * 8 + ((0 + q) ^ (col & 7));
    int ro_m1 = 128 + col * 8 + ((4 + q) ^ (col & 7));

    // prefill: tiles 0..3 into set A; issue loads for tiles 4..7
    uint4 r0 = *(const uint4*)(sb0);
    uint4 r1 = *(const uint4*)(sb0 + 1024);
    uint4 r2 = *(const uint4*)(sb0 + 2048);
    uint4 r3 = *(const uint4*)(sb0 + 3072);
    smem[0][woff] = r0; smem[1][woff] = r1;
    smem[2][woff] = r2; smem[3][woff] = r3;
    r0 = *(const uint4*)(sb0 + 4096);
    r1 = *(const uint4*)(sb0 + 5120);
    r2 = *(const uint4*)(sb0 + 6144);
    r3 = *(const uint4*)(sb0 + 7168);
    __syncthreads();

    for (int rd = 0; rd < 16; ++rd) {
        int base = (rd & 1) << 2;    // set being read
        int nb = 4 - base;           // set being written (next round's tiles)
        if (rd < 15) {
            smem[nb + 0][woff] = r0; smem[nb + 1][woff] = r1;
            smem[nb + 2][woff] = r2; smem[nb + 3][woff] = r3;
            if (rd < 14) {           // loads for round rd+2 (vmcnt slack = 1 round)
                const ushort* ld = sb0 + (size_t)(rd + 2) * 4096;
                r0 = *(const uint4*)(ld);
                r1 = *(const uint4*)(ld + 1024);
                r2 = *(const uint4*)(ld + 2048);
                r3 = *(const uint4*)(ld + 3072);
            }
        }
#pragma unroll
        for (int sub = 0; sub < 4; ++sub) {
            int c0 = (rd * 4 + sub) * 16;
            float4 bq = *(const float4*)(Bc + c0 + q4);
            short8 Ah0 = *(const short8*)&smem[base + sub][ro_h0];
            short8 Ah1 = *(const short8*)&smem[base + sub][ro_h1];
            short8 Am0 = *(const short8*)&smem[base + sub][ro_m0];
            short8 Am1 = *(const short8*)&smem[base + sub][ro_m1];
            int bv = c0 + q4;
            float bqv[4] = {bq.x, bq.y, bq.z, bq.w};
#pragma unroll
            for (int tt = 0; tt < 2; ++tt) {
                f32x4 acc = {0.f, 0.f, 0.f, 0.f};
                acc = __builtin_amdgcn_mfma_f32_16x16x32_bf16(Ah0, Xhi[tt][0], acc, 0, 0, 0);
                acc = __builtin_amdgcn_mfma_f32_16x16x32_bf16(Ah1, Xhi[tt][1], acc, 0, 0, 0);
                acc = __builtin_amdgcn_mfma_f32_16x16x32_bf16(Ah0, Xmid[tt][0], acc, 0, 0, 0);
                acc = __builtin_amdgcn_mfma_f32_16x16x32_bf16(Ah1, Xmid[tt][1], acc, 0, 0, 0);
                acc = __builtin_amdgcn_mfma_f32_16x16x32_bf16(Am0, Xhi[tt][0], acc, 0, 0, 0);
                acc = __builtin_amdgcn_mfma_f32_16x16x32_bf16(Am1, Xhi[tt][1], acc, 0, 0, 0);
#pragma unroll
                for (int rr = 0; rr < 4; ++rr) {
                    float d = fmaf(-2.f, acc[rr], bqv[rr]);
                    bool lt = d < best[tt][rr];
                    sec[tt][rr] = __builtin_amdgcn_fmed3f(d, best[tt][rr], sec[tt][rr]);
                    best[tt][rr] = fminf(best[tt][rr], d);
                    bbase[tt][rr] = lt ? bv : bbase[tt][rr];
                }
            }
        }
        __syncthreads();   // single barrier per round
    }

#pragma unroll
    for (int tt = 0; tt < 2; ++tt) {
        float b = best[tt][0], s2 = sec[tt][0];
        int bi = bbase[tt][0];
#pragma unroll
        for (int rr = 1; rr < 4; ++rr) {
            float ob = best[tt][rr];
            int oi = bbase[tt][rr] + rr;
            s2 = fminf(fminf(s2, sec[tt][rr]), fmaxf(b, ob));
            bool lt2 = (ob < b) || (ob == b && oi < bi);
            b = lt2 ? ob : b; bi = lt2 ? oi : bi;
        }
#pragma unroll
        for (int off = 16; off <= 32; off <<= 1) {
            float ob = __shfl_xor(b, off, 64);
            float os = __shfl_xor(s2, off, 64);
            int   oi = __shfl_xor(bi, off, 64);
            s2 = fminf(fminf(s2, os), fmaxf(b, ob));
            bool lt = (ob < b) || (ob == b && oi < bi);
            b = lt ? ob : b; bi = lt ? oi : bi;
        }
        if (lane < 16) {
            int token = tokb + tt * 16 + lane;
            out[IDXOFF + token] = (float)bi;
            idxs[wv * 32 + tt * 16 + lane] = bi;
            if (s2 - b < MARGIN) {
                int pos = atomicAdd((int*)ws + OFF_RCNT, 1);
                if (pos < RCAP) ((int*)ws)[OFF_RLIST + pos] = token;
            }
        }
    }
    __syncthreads();

    // fused quantized + loss epilogue (refine later corrects flagged rows)
    float se = 0.f;
    int tokb0 = blockIdx.x * 128;
#pragma unroll
    for (int i = 0; i < 8; ++i) {
        int gi = i * 256 + tid;
        int tok = gi >> 4, qd = gi & 15;
        int ci = idxs[tok];
        float4 xvv = *(const float4*)(x + (size_t)(tokb0 + tok) * 64 + qd * 4);
        float4 qv = *(const float4*)(cbf + (size_t)ci * 64 + qd * 4);
        float d0 = qv.x - xvv.x, d1 = qv.y - xvv.y;
        float d2 = qv.z - xvv.z, d3 = qv.w - xvv.w;
        float4 o;
        o.x = xvv.x + d0; o.y = xvv.y + d1; o.z = xvv.z + d2; o.w = xvv.w + d3;
        *(float4*)(out + (size_t)(tokb0 + tok) * 64 + qd * 4) = o;
        se += d0 * d0 + d1 * d1 + d2 * d2 + d3 * d3;
    }
    for (int off = 32; off; off >>= 1) se += __shfl_down(se, off, 64);
    if (lane == 0) red[wv] = se;
    __syncthreads();
    if (tid == 0) ws[OFF_BLK + blockIdx.x] = (red[0] + red[1]) + (red[2] + red[3]);
}

// exact fp32 re-scan for flagged tokens; fixes quantized rows + loss delta.
__global__ __launch_bounds__(256) void vq_refine(const float* __restrict__ x,
                                                 const float* __restrict__ cb,
                                                 float* __restrict__ out,
                                                 float* __restrict__ ws) {
    __shared__ float ctile[128][64];               // 32KB
    __shared__ float xs[8][64];
    __shared__ float As[8];
    __shared__ int   tokid[8], oidx[8], nidx[8];
    __shared__ unsigned long long rkeys[8][128];   // 8KB
    __shared__ float dred[4];

    int cnt = min(((int*)ws)[OFF_RCNT], RCAP);
    if (cnt <= 0) return;
    int ngroups = (cnt + 7) >> 3;
    int tid = threadIdx.x;
    int code = tid & 127, th = tid >> 7;

    for (int grp = blockIdx.x; grp < ngroups; grp += gridDim.x) {
        if (tid < 8) {
            int i = grp * 8 + tid;
            int t = ((int*)ws)[OFF_RLIST + min(i, cnt - 1)];
            tokid[tid] = t;
            oidx[tid] = (int)out[IDXOFF + t];
        }
        __syncthreads();
#pragma unroll
        for (int it = 0; it < 2; ++it) {
            int idx = it * 256 + tid;
            xs[idx >> 6][idx & 63] = x[(size_t)tokid[idx >> 6] * 64 + (idx & 63)];
        }
        __syncthreads();
        if (tid < 8) {   // exact R2 A-chain
            float a0 = 0.f, a1 = 0.f, a2 = 0.f, a3 = 0.f;
#pragma unroll
            for (int kc = 0; kc < 16; ++kc) {
                float4 xk = *(const float4*)(xs[tid] + kc * 4);
                a0 = fmaf(xk.x, xk.x, a0); a1 = fmaf(xk.y, xk.y, a1);
                a2 = fmaf(xk.z, xk.z, a2); a3 = fmaf(xk.w, xk.w, a3);
            }
            As[tid] = (a0 + a1) + (a2 + a3);
        }

        unsigned long long bk[4] = {~0ull, ~0ull, ~0ull, ~0ull};
        int tb = th * 4;

        for (int pass = 0; pass < 8; ++pass) {
            int cbase = pass * 128;
            __syncthreads();
#pragma unroll
            for (int it = 0; it < 8; ++it) {
                int gi = it * 256 + tid;
                int cc = gi >> 4, qq = gi & 15;
                float4 v = *(const float4*)(cb + (size_t)(cbase + cc) * 64 + qq * 4);
                *(float4*)&ctile[cc][(qq ^ (cc & 15)) * 4] = v;
            }
            __syncthreads();

            float p0 = 0.f, p1 = 0.f, p2 = 0.f, p3 = 0.f;
#pragma unroll
            for (int qq = 0; qq < 16; ++qq) {
                float4 cv = *(const float4*)&ctile[code][(qq ^ (code & 15)) * 4];
                float4 x0 = *(const float4*)(xs[tb + 0] + qq * 4);
                float4 x1 = *(const float4*)(xs[tb + 1] + qq * 4);
                float4 x2 = *(const float4*)(xs[tb + 2] + qq * 4);
                float4 x3 = *(const float4*)(xs[tb + 3] + qq * 4);
                p0 = fmaf(x0.x, cv.x, p0); p0 = fmaf(x0.y, cv.y, p0);
                p0 = fmaf(x0.z, cv.z, p0); p0 = fmaf(x0.w, cv.w, p0);
                p1 = fmaf(x1.x, cv.x, p1); p1 = fmaf(x1.y, cv.y, p1);
                p1 = fmaf(x1.z, cv.z, p1); p1 = fmaf(x1.w, cv.w, p1);
                p2 = fmaf(x2.x, cv.x, p2); p2 = fmaf(x2.y, cv.y, p2);
                p2 = fmaf(x2.z, cv.z, p2); p2 = fmaf(x2.w, cv.w, p2);
                p3 = fmaf(x3.x, cv.x, p3); p3 = fmaf(x3.y, cv.y, p3);
                p3 = fmaf(x3.z, cv.z, p3); p3 = fmaf(x3.w, cv.w, p3);
            }
            float bn = ws[OFF_BC + cbase + code];
            int gcode = cbase + code;
            float pv[4] = {p0, p1, p2, p3};
#pragma unroll
            for (int j = 0; j < 4; ++j) {
                float s = As[tb + j] + bn;
                float d = fmaf(-2.0f, pv[j], s);   // == fl(s - 2p)
                unsigned long long key =
                    (((unsigned long long)__float_as_uint(d)) << 32) | (unsigned)gcode;
                bk[j] = min(bk[j], key);
            }
        }
        __syncthreads();
#pragma unroll
        for (int j = 0; j < 4; ++j) rkeys[tb + j][code] = bk[j];
        __syncthreads();

        int wv2 = tid >> 6, lane = tid & 63;
#pragma unroll
        for (int u = 0; u < 2; ++u) {
            int tt = wv2 * 2 + u;
            unsigned long long k = min(rkeys[tt][lane], rkeys[tt][lane + 64]);
#pragma unroll
            for (int off = 32; off; off >>= 1)
                k = min(k, (unsigned long long)__shfl_xor((long long)k, off, 64));
            if (lane == 0) {
                int ni = (int)(unsigned)(k & 0xffffffffull);
                nidx[tt] = ni;
                if (grp * 8 + tt < cnt) out[IDXOFF + tokid[tt]] = (float)ni;
            }
        }
        __syncthreads();

        float delta = 0.f;
        {
            int tok = tid >> 5, e2 = (tid & 31) * 2;
            if (grp * 8 + tok < cnt) {
                int nw = nidx[tok], od = oidx[tok];
                if (nw != od) {
                    float x0 = xs[tok][e2], x1 = xs[tok][e2 + 1];
                    float qn0 = cb[(size_t)nw * 64 + e2], qn1 = cb[(size_t)nw * 64 + e2 + 1];
                    float qo0 = cb[(size_t)od * 64 + e2], qo1 = cb[(size_t)od * 64 + e2 + 1];
                    float dn0 = qn0 - x0, dn1 = qn1 - x1;
                    float do0 = qo0 - x0, do1 = qo1 - x1;
                    out[(size_t)tokid[tok] * 64 + e2]     = x0 + dn0;
                    out[(size_t)tokid[tok] * 64 + e2 + 1] = x1 + dn1;
                    delta = (dn0 * dn0 + dn1 * dn1) - (do0 * do0 + do1 * do1);
                }
            }
        }
        for (int off = 32; off; off >>= 1) delta += __shfl_down(delta, off, 64);
        if ((tid & 63) == 0) dred[tid >> 6] = delta;
        __syncthreads();
        if (tid == 0) {
            float dsum = (dred[0] + dred[1]) + (dred[2] + dred[3]);
            if (dsum != 0.f) atomicAdd(ws + OFF_CORR, dsum);
        }
        __syncthreads();
    }
}

__global__ __launch_bounds__(256) void vq_loss2(float* __restrict__ out,
                                                const float* __restrict__ ws) {
    const float* blk = ws + OFF_BLK;
    __shared__ double sd[256];
    double s = 0.0;
    for (int i = threadIdx.x; i < 2048; i += 256) s += (double)blk[i];
    sd[threadIdx.x] = s;
    __syncthreads();
    for (int off = 128; off; off >>= 1) {
        if (threadIdx.x < off) sd[threadIdx.x] += sd[threadIdx.x + off];
        __syncthreads();
    }
    if (threadIdx.x == 0) {
        double tot = sd[0] + (double)ws[OFF_CORR];
        out[LOSSOFF] = (float)(1.25 * tot / ((double)NTOK * (double)DIM));
    }
}

extern "C" void kernel_launch(void* const* d_in, const int* in_sizes, int n_in,
                              void* d_out, int out_size, void* d_ws, size_t ws_size,
                              hipStream_t stream) {
    (void)in_sizes; (void)n_in; (void)out_size; (void)ws_size;
    const float* x = (const float*)d_in[0];
    const float* cb = (const float*)d_in[1];
    float* out = (float*)d_out;
    float* ws = (float*)d_ws;

    hipLaunchKernelGGL(vq_prep_cb, dim3(4), dim3(256), 0, stream, cb, ws);
    hipLaunchKernelGGL(vq_mfma, dim3(2048), dim3(256), 0, stream, x, cb, out, ws);
    hipLaunchKernelGGL(vq_refine, dim3(1024), dim3(256), 0, stream, x, cb, out, ws);
    hipLaunchKernelGGL(vq_loss2, dim3(1), dim3(256), 0, stream, out, ws);
}